// Round 1
// baseline (1027.290 us; speedup 1.0000x reference)
//
#include <hip/hip_runtime.h>
#include <hip/hip_bf16.h>
#include <stdint.h>

#define N_NODES 50000
#define N_EDGES 800000
#define H 128

typedef short bf16x8 __attribute__((ext_vector_type(8)));
typedef float f32x4 __attribute__((ext_vector_type(4)));

__device__ __forceinline__ short f2bfs(float f) {
    __hip_bfloat16 h = __float2bfloat16(f);   // HW RNE cvt on gfx950
    return *(short*)&h;
}

__device__ __forceinline__ bf16x8 cvt8(const float* __restrict__ p) {
    const float4* q = (const float4*)p;
    float4 a = q[0], b = q[1];
    bf16x8 r;
    r[0] = f2bfs(a.x); r[1] = f2bfs(a.y); r[2] = f2bfs(a.z); r[3] = f2bfs(a.w);
    r[4] = f2bfs(b.x); r[5] = f2bfs(b.y); r[6] = f2bfs(b.z); r[7] = f2bfs(b.w);
    return r;
}

// ---- weight repack: fp32 [K x 128] -> bf16 fragment-linear [kt][nt][lane][8]
// element (kt,nt,lane,j) = W[(kt*32 + (lane>>4)*8 + j) * 128 + nt*16 + (lane&15)]
// buffers (bf16 elem offsets in ws):
//   BW1 @ 0      (We1, K=384, 96 frags, 49152 elems)
//   BW2 @ 49152  (We2, K=128, 32 frags, 16384 elems)
//   BN1 @ 65536  (Wn1, K=256, 64 frags, 32768 elems)
//   BN2 @ 98304  (Wn2, K=128, 32 frags, 16384 elems)   total 114688
__global__ void prep_weights(const float* __restrict__ We1, const float* __restrict__ We2,
                             const float* __restrict__ Wn1, const float* __restrict__ Wn2,
                             unsigned short* __restrict__ wb) {
    int i = blockIdx.x * 256 + threadIdx.x;
    if (i >= 114688) return;
    const float* W; int idx;
    if (i < 49152)      { W = We1; idx = i; }
    else if (i < 65536) { W = We2; idx = i - 49152; }
    else if (i < 98304) { W = Wn1; idx = i - 65536; }
    else                { W = Wn2; idx = i - 98304; }
    int f = idx >> 9, lane = (idx >> 3) & 63, j = idx & 7;
    int kt = f >> 3, nt = f & 7;
    int k = kt * 32 + (lane >> 4) * 8 + j;
    int n = nt * 16 + (lane & 15);
    wb[i] = (unsigned short)f2bfs(W[k * H + n]);
}

// ---- edge MLP + scatter-add.  1 wave = 32 edges (2 M-tiles of 16), block = 4 waves.
__launch_bounds__(256)
__global__ void edge_mlp(const float* __restrict__ x,
                         const int* __restrict__ ei,
                         const float* __restrict__ ea,
                         const float* __restrict__ be1,
                         const float* __restrict__ be2,
                         const unsigned short* __restrict__ wb,
                         float* __restrict__ agg) {
    // per-wave h staging in GEMM2-A fragment order: [wave][t][kt2][lane][8]
    __shared__ short hbuf[4][2][4][64][8];   // 32 KiB
    const int tid = threadIdx.x;
    const int wave = tid >> 6, lane = tid & 63;
    const int c = lane & 15, quad = lane >> 4;
    const int e0 = (blockIdx.x * 4 + wave) * 32;

    const bf16x8* __restrict__ BW1 = (const bf16x8*)wb;
    const bf16x8* __restrict__ BW2 = (const bf16x8*)(wb + 49152);

    float be1v[8], be2v[8];
#pragma unroll
    for (int nt = 0; nt < 8; ++nt) {
        be1v[nt] = be1[nt * 16 + c];
        be2v[nt] = be2[nt * 16 + c];
    }

    // A-row segment pointers per M-tile: {x[row], x[col], edge_attr}
    const float* pa[2][3];
#pragma unroll
    for (int t = 0; t < 2; ++t) {
        int e = e0 + t * 16 + c;
        int r  = ei[e];
        int cl = ei[N_EDGES + e];
        pa[t][0] = x + (size_t)r * H;
        pa[t][1] = x + (size_t)cl * H;
        pa[t][2] = ea + (size_t)e * H;
    }

    f32x4 acc[2][8];
#pragma unroll
    for (int t = 0; t < 2; ++t)
#pragma unroll
        for (int nt = 0; nt < 8; ++nt)
            acc[t][nt] = (f32x4){be1v[nt], be1v[nt], be1v[nt], be1v[nt]};

#pragma unroll
    for (int kt = 0; kt < 12; ++kt) {
        const int seg = kt >> 2;
        const int off = (kt & 3) * 32 + quad * 8;
        bf16x8 a0 = cvt8(pa[0][seg] + off);
        bf16x8 a1 = cvt8(pa[1][seg] + off);
#pragma unroll
        for (int nt = 0; nt < 8; ++nt) {
            bf16x8 b = BW1[(kt * 8 + nt) * 64 + lane];
            acc[0][nt] = __builtin_amdgcn_mfma_f32_16x16x32_bf16(a0, b, acc[0][nt], 0, 0, 0);
            acc[1][nt] = __builtin_amdgcn_mfma_f32_16x16x32_bf16(a1, b, acc[1][nt], 0, 0, 0);
        }
    }

    // relu + store h to LDS in GEMM2 A-fragment order.
    // producer value sits at (m = quad*4+r, n = nt*16+c); consumer slot:
    // kt2 = n>>5, lane' = m + 16*((n>>3)&3), j = n&7
#pragma unroll
    for (int t = 0; t < 2; ++t)
#pragma unroll
        for (int nt = 0; nt < 8; ++nt) {
            int kt2 = nt >> 1;
            int laneq = 16 * ((nt * 2 + (c >> 3)) & 3);
#pragma unroll
            for (int r = 0; r < 4; ++r) {
                float v = acc[t][nt][r];
                v = v > 0.f ? v : 0.f;
                hbuf[wave][t][kt2][quad * 4 + r + laneq][c & 7] = f2bfs(v);
            }
        }
    __syncthreads();

    f32x4 acc2[2][8];
#pragma unroll
    for (int t = 0; t < 2; ++t)
#pragma unroll
        for (int nt = 0; nt < 8; ++nt)
            acc2[t][nt] = (f32x4){be2v[nt], be2v[nt], be2v[nt], be2v[nt]};

#pragma unroll
    for (int kt = 0; kt < 4; ++kt) {
        bf16x8 a0 = *(const bf16x8*)&hbuf[wave][0][kt][lane][0];
        bf16x8 a1 = *(const bf16x8*)&hbuf[wave][1][kt][lane][0];
#pragma unroll
        for (int nt = 0; nt < 8; ++nt) {
            bf16x8 b = BW2[(kt * 8 + nt) * 64 + lane];
            acc2[0][nt] = __builtin_amdgcn_mfma_f32_16x16x32_bf16(a0, b, acc2[0][nt], 0, 0, 0);
            acc2[1][nt] = __builtin_amdgcn_mfma_f32_16x16x32_bf16(a1, b, acc2[1][nt], 0, 0, 0);
        }
    }

    // scatter-add messages into agg by destination (col) node
    int ce[2][4];
#pragma unroll
    for (int t = 0; t < 2; ++t)
#pragma unroll
        for (int r = 0; r < 4; ++r)
            ce[t][r] = ei[N_EDGES + e0 + t * 16 + quad * 4 + r];

#pragma unroll
    for (int t = 0; t < 2; ++t)
#pragma unroll
        for (int nt = 0; nt < 8; ++nt)
#pragma unroll
            for (int r = 0; r < 4; ++r)
                atomicAdd(agg + (size_t)ce[t][r] * H + nt * 16 + c, acc2[t][nt][r]);
}

// ---- node MLP: inputs concat(x[v], agg[v]) [N x 256] -> 128 -> 128
__launch_bounds__(256)
__global__ void node_mlp(const float* __restrict__ x,
                         const float* __restrict__ agg,
                         const float* __restrict__ bn1,
                         const float* __restrict__ bn2,
                         const unsigned short* __restrict__ wb,
                         float* __restrict__ out) {
    __shared__ short hbuf[4][2][4][64][8];
    const int tid = threadIdx.x;
    const int wave = tid >> 6, lane = tid & 63;
    const int c = lane & 15, quad = lane >> 4;
    const int v0 = (blockIdx.x * 4 + wave) * 32;

    const bf16x8* __restrict__ BN1 = (const bf16x8*)(wb + 65536);
    const bf16x8* __restrict__ BN2 = (const bf16x8*)(wb + 98304);

    float b1v[8], b2v[8];
#pragma unroll
    for (int nt = 0; nt < 8; ++nt) {
        b1v[nt] = bn1[nt * 16 + c];
        b2v[nt] = bn2[nt * 16 + c];
    }

    const float* pa[2][2];
#pragma unroll
    for (int t = 0; t < 2; ++t) {
        int v = v0 + t * 16 + c;
        v = v < N_NODES ? v : N_NODES - 1;   // clamp; garbage rows never stored
        pa[t][0] = x   + (size_t)v * H;
        pa[t][1] = agg + (size_t)v * H;
    }

    f32x4 acc[2][8];
#pragma unroll
    for (int t = 0; t < 2; ++t)
#pragma unroll
        for (int nt = 0; nt < 8; ++nt)
            acc[t][nt] = (f32x4){b1v[nt], b1v[nt], b1v[nt], b1v[nt]};

#pragma unroll
    for (int kt = 0; kt < 8; ++kt) {
        const int seg = kt >> 2;
        const int off = (kt & 3) * 32 + quad * 8;
        bf16x8 a0 = cvt8(pa[0][seg] + off);
        bf16x8 a1 = cvt8(pa[1][seg] + off);
#pragma unroll
        for (int nt = 0; nt < 8; ++nt) {
            bf16x8 b = BN1[(kt * 8 + nt) * 64 + lane];
            acc[0][nt] = __builtin_amdgcn_mfma_f32_16x16x32_bf16(a0, b, acc[0][nt], 0, 0, 0);
            acc[1][nt] = __builtin_amdgcn_mfma_f32_16x16x32_bf16(a1, b, acc[1][nt], 0, 0, 0);
        }
    }

#pragma unroll
    for (int t = 0; t < 2; ++t)
#pragma unroll
        for (int nt = 0; nt < 8; ++nt) {
            int kt2 = nt >> 1;
            int laneq = 16 * ((nt * 2 + (c >> 3)) & 3);
#pragma unroll
            for (int r = 0; r < 4; ++r) {
                float v = acc[t][nt][r];
                v = v > 0.f ? v : 0.f;
                hbuf[wave][t][kt2][quad * 4 + r + laneq][c & 7] = f2bfs(v);
            }
        }
    __syncthreads();

    f32x4 acc2[2][8];
#pragma unroll
    for (int t = 0; t < 2; ++t)
#pragma unroll
        for (int nt = 0; nt < 8; ++nt)
            acc2[t][nt] = (f32x4){b2v[nt], b2v[nt], b2v[nt], b2v[nt]};

#pragma unroll
    for (int kt = 0; kt < 4; ++kt) {
        bf16x8 a0 = *(const bf16x8*)&hbuf[wave][0][kt][lane][0];
        bf16x8 a1 = *(const bf16x8*)&hbuf[wave][1][kt][lane][0];
#pragma unroll
        for (int nt = 0; nt < 8; ++nt) {
            bf16x8 b = BN2[(kt * 8 + nt) * 64 + lane];
            acc2[0][nt] = __builtin_amdgcn_mfma_f32_16x16x32_bf16(a0, b, acc2[0][nt], 0, 0, 0);
            acc2[1][nt] = __builtin_amdgcn_mfma_f32_16x16x32_bf16(a1, b, acc2[1][nt], 0, 0, 0);
        }
    }

#pragma unroll
    for (int t = 0; t < 2; ++t)
#pragma unroll
        for (int nt = 0; nt < 8; ++nt)
#pragma unroll
            for (int r = 0; r < 4; ++r) {
                int v = v0 + t * 16 + quad * 4 + r;
                if (v < N_NODES)
                    out[(size_t)v * H + nt * 16 + c] = acc2[t][nt][r];
            }
}

extern "C" void kernel_launch(void* const* d_in, const int* in_sizes, int n_in,
                              void* d_out, int out_size, void* d_ws, size_t ws_size,
                              hipStream_t stream) {
    const float* x   = (const float*)d_in[0];
    const int*   ei  = (const int*)d_in[1];
    const float* ea  = (const float*)d_in[2];
    const float* We1 = (const float*)d_in[3];
    const float* be1 = (const float*)d_in[4];
    const float* We2 = (const float*)d_in[5];
    const float* be2 = (const float*)d_in[6];
    const float* Wn1 = (const float*)d_in[7];
    const float* bn1 = (const float*)d_in[8];
    const float* Wn2 = (const float*)d_in[9];
    const float* bn2 = (const float*)d_in[10];
    float* out = (float*)d_out;

    unsigned short* wb = (unsigned short*)d_ws;                 // 224 KiB weight frags
    float* agg = (float*)((char*)d_ws + (256 << 10));           // 25.6 MB accumulator

    hipMemsetAsync(agg, 0, (size_t)N_NODES * H * sizeof(float), stream);
    prep_weights<<<448, 256, 0, stream>>>(We1, We2, Wn1, Wn2, wb);
    edge_mlp<<<6250, 256, 0, stream>>>(x, ei, ea, be1, be2, wb, agg);
    node_mlp<<<391, 256, 0, stream>>>(x, agg, bn1, bn2, wb, out);
}